// Round 9
// baseline (264.575 us; speedup 1.0000x reference)
//
#include <hip/hip_runtime.h>
#include <hip/hip_fp16.h>

#define D 48
#define KORD 4
#define RSH 7             // 128 dst ids per bucket
#define RNG 128
#define NBK 391           // ceil(50000/128)
#define HB 64             // histogram chunks
#define HHALF 25000       // node ids per half
#define HW 12500          // packed words per half
#define MAXB 6144         // max PADDED entries per bucket
#define PADB 960          // per-bucket slack for 8-rounding (multiple of 8)

// ---- outdeg histogram (privatized, no global atomics) + coarse bucket hist ----
__global__ __launch_bounds__(1024) void k_hist(const int* __restrict__ row,
        const int* __restrict__ col, uint* __restrict__ histbuf,
        uint* __restrict__ coarse, int E, int chunk) {
    __shared__ uint hist[HW];     // 50 KB: packed ushort counters for one id-half
    __shared__ uint ch[NBK];
    int k = blockIdx.x >> 1, h = blockIdx.x & 1;
    int tid = threadIdx.x;
    for (int i = tid; i < HW; i += 1024) hist[i] = 0;
    if (h == 0) for (int i = tid; i < NBK; i += 1024) ch[i] = 0;
    __syncthreads();
    int lo = h * HHALF;
    int s = k * chunk, e = min(E, s + chunk);
    for (int i = s + tid; i < e; i += 1024) {
        int r = row[i], c = col[i];
        if (r != c) {
            unsigned rl = (unsigned)(r - lo);
            if (rl < HHALF) atomicAdd(&hist[rl >> 1], 1u << ((rl & 1) * 16));
            if (h == 0) atomicAdd(&ch[c >> RSH], 1u);
        }
    }
    __syncthreads();
    uint* dst = histbuf + (size_t)k * (2 * HW) + (size_t)h * HW;
    for (int i = tid; i < HW; i += 1024) dst[i] = hist[i];
    if (h == 0) for (int i = tid; i < NBK; i += 1024) atomicAdd(&coarse[i], ch[i]);
}

// ---- reduce private histograms -> dis = deg^{-1/2} ----
__global__ void k_reduce(const uint* __restrict__ histbuf, float* __restrict__ dis,
                         int nwords) {
    int t = blockIdx.x * blockDim.x + threadIdx.x;  // word t = nodes 2t,2t+1
    if (t >= nwords) return;
    uint lo = 0, hi = 0;
#pragma unroll 8
    for (int k = 0; k < HB; ++k) {
        uint w = histbuf[(size_t)k * (2 * HW) + t];
        lo += w & 0xFFFFu;
        hi += w >> 16;
    }
    float2 d;
    d.x = lo ? rsqrtf((float)lo) : 0.0f;
    d.y = hi ? rsqrtf((float)hi) : 0.0f;
    *(float2*)(dis + 2 * t) = d;
}

// ---- scan coarse bucket counts -> base, init cursors ----
__global__ void k_cscan(const uint* __restrict__ coarse, int* __restrict__ base,
                        int* __restrict__ cursor, int nbk) {
    int lane = threadIdx.x;
    int carry = 0;
    for (int s = 0; s < nbk; s += 64) {
        int i = s + lane;
        int v = (i < nbk) ? (int)coarse[i] : 0;
        int incl = v;
#pragma unroll
        for (int off = 1; off < 64; off <<= 1) {
            int t = __shfl_up(incl, off);
            if (lane >= off) incl += t;
        }
        if (i < nbk) { int ex = carry + incl - v; base[i] = ex; cursor[i] = ex; }
        carry += __shfl(incl, 63);
    }
    if (lane == 0) base[nbk] = carry;
}

// ---- pass 1: per-block count -> one reservation atomic per bucket -> direct scatter ----
__global__ __launch_bounds__(256) void k_scatter1(const int* __restrict__ row,
        const int* __restrict__ col, int* __restrict__ cursor,
        uint* __restrict__ bdata, int E, int chunk) {
    __shared__ uint cnt[NBK];
    __shared__ uint cur[NBK];
    int tid = threadIdx.x;
    int s = blockIdx.x * chunk, e = min(E, s + chunk);
    for (int i = tid; i < NBK; i += 256) cnt[i] = 0;
    __syncthreads();
    for (int i = s + tid; i < e; i += 256) {
        int r = row[i], c = col[i];
        if (r != c) atomicAdd(&cnt[c >> RSH], 1u);
    }
    __syncthreads();
    for (int i = tid; i < NBK; i += 256) {
        uint c = cnt[i];
        cur[i] = c ? (uint)atomicAdd(&cursor[i], (int)c) : 0u;  // global run base
    }
    __syncthreads();
    for (int i = s + tid; i < e; i += 256) {
        int r = row[i], c = col[i];
        if (r != c) {
            uint p = atomicAdd(&cur[c >> RSH], 1u);
            bdata[p] = ((uint)c << 16) | (uint)r;
        }
    }
}

// ---- pass 2: per-bucket counting sort -> padded csr (u16, sentinel-filled) ----
// per-node region rounded to 8 entries, 8-aligned start; pads = sentinel id N
__global__ __launch_bounds__(256) void k_scatter2(const uint* __restrict__ bdata,
        const int* __restrict__ base, int* __restrict__ offs, int* __restrict__ cntout,
        unsigned short* __restrict__ csr, int N) {
    __shared__ uint cnt[RNG], locp[RNG], cur[RNG];
    __shared__ uint s_tot;
    __shared__ unsigned short srcbuf[MAXB];
    int b = blockIdx.x, tid = threadIdx.x;
    int s0 = base[b], e2 = base[b + 1];
    int m = e2 - s0;
    int sp = ((s0 + 7) & ~7) + PADB * b;   // padded, 8-aligned region start
    int dstbase = b << RSH;
    for (int i = tid; i < RNG; i += 256) cnt[i] = 0;
    __syncthreads();
    for (int i = tid; i < m; i += 256) {
        uint u = bdata[s0 + i];
        atomicAdd(&cnt[(u >> 16) & (RNG - 1)], 1u);
    }
    __syncthreads();
    if (tid < 64) {  // scan of round8(counts) in wave 0
        uint carry = 0;
        for (int r0 = 0; r0 < RNG; r0 += 64) {
            uint v = (cnt[r0 + tid] + 7u) & ~7u;
            uint incl = v;
#pragma unroll
            for (int off = 1; off < 64; off <<= 1) {
                uint t = __shfl_up(incl, off);
                if (tid >= off) incl += t;
            }
            locp[r0 + tid] = carry + incl - v;
            carry += __shfl(incl, 63);
        }
        if (tid == 0) s_tot = carry;
    }
    __syncthreads();
    uint tot = s_tot;
    if (tid < RNG) {
        int node = dstbase + tid;
        if (node < N) {
            offs[node] = sp + (int)locp[tid];
            cntout[node] = (int)((cnt[tid] + 7u) & ~7u);
        }
        cur[tid] = locp[tid];
    }
    for (uint i = tid; i < tot; i += 256) srcbuf[i] = (unsigned short)N;  // sentinel
    __syncthreads();
    for (int i = tid; i < m; i += 256) {
        uint u = bdata[s0 + i];
        uint slot = atomicAdd(&cur[(u >> 16) & (RNG - 1)], 1u);
        srcbuf[slot] = (unsigned short)(u & 0xFFFFu);
    }
    __syncthreads();
    for (uint i = tid; i < tot; i += 256) csr[sp + i] = srcbuf[i];
}

// ---- x -> fp16 shadow, pre-scaled by dis[i]; sentinel rows (xh, t1h) = zeros ----
__global__ void k_h2(const float* __restrict__ x, const float* __restrict__ dis,
                     __half* __restrict__ xh, __half* __restrict__ t1h, int n) {
    int t = blockIdx.x * blockDim.x + threadIdx.x;
    if (t >= (n + 1) * 12) return;
    int node = t / 12, c4 = t % 12;
    if (node == n) {  // sentinel rows
        uint2 z = make_uint2(0u, 0u);
        *(uint2*)(xh + node * D + c4 * 4) = z;
        *(uint2*)(t1h + node * D + c4 * 4) = z;
        return;
    }
    float d = dis[node];
    float4 v = *(const float4*)(x + node * D + c4 * 4);
    __half2* p = (__half2*)(xh + node * D + c4 * 4);
    p[0] = __floats2half2_rn(d * v.x, d * v.y);
    p[1] = __floats2half2_rn(d * v.z, d * v.w);
}

// extract 16-bit id j (0..7) from a uint4 of 8 packed u16
__device__ inline uint ext16(const uint4& p, int j) {
    uint w = (j < 4) ? ((j < 2) ? p.x : p.y) : ((j < 6) ? p.z : p.w);
    return (j & 1) ? (w >> 16) : (w & 0xFFFFu);
}

// ---- propagation v5: 16B/lane gathers, 8 edges per gather instruction ----
// wave per node; lanes 0..47: slot s=lane/6 (edge), part p=lane%6 (8 halfs)
// r = -alpha * dis[i] * sum_e tab[src_e] - subH ; sentinel rows are zero
__global__ __launch_bounds__(256) void k_prop(const __half* __restrict__ tab,
        const float* __restrict__ subH, float* __restrict__ dstF,
        __half* __restrict__ dstH, const int* __restrict__ offs,
        const int* __restrict__ cnt, const unsigned short* __restrict__ csr,
        const float* __restrict__ dis, int n, float alpha, int scaleShadow) {
    int gw = (blockIdx.x * blockDim.x + threadIdx.x) >> 6;
    if (gw >= n) return;
    gw = __builtin_amdgcn_readfirstlane(gw);
    const int lane = threadIdx.x & 63;
    const int s = lane / 6;           // edge slot 0..7 (lanes 48..63 idle)
    const int p = lane % 6;           // halfs 8p..8p+7 of the row
    const int off = __builtin_amdgcn_readfirstlane(offs[gw]);
    const int c8 = __builtin_amdgcn_readfirstlane(cnt[gw]);  // multiple of 8
    float a0 = 0.f, a1 = 0.f, a2 = 0.f, a3 = 0.f;
    float a4 = 0.f, a5 = 0.f, a6 = 0.f, a7 = 0.f;
    if (lane < 48) {
        const unsigned short* cp = csr + off;       // 16B-aligned
        const uint4* tq = (const uint4*)tab;        // row = 6 uint4 (96B)
#define ACC8(G)                                                             \
        {                                                                   \
            float2 f0 = __half22float2(*(__half2*)&(G).x);                  \
            float2 f1 = __half22float2(*(__half2*)&(G).y);                  \
            float2 f2 = __half22float2(*(__half2*)&(G).z);                  \
            float2 f3 = __half22float2(*(__half2*)&(G).w);                  \
            a0 += f0.x; a1 += f0.y; a2 += f1.x; a3 += f1.y;                 \
            a4 += f2.x; a5 += f2.y; a6 += f3.x; a7 += f3.y;                 \
        }
        int b = 0;
        for (; b + 32 <= c8; b += 32) {   // 32 rows in flight, 4 gather instrs
            uint4 i0 = *(const uint4*)(cp + b);
            uint4 i1 = *(const uint4*)(cp + b + 8);
            uint4 i2 = *(const uint4*)(cp + b + 16);
            uint4 i3 = *(const uint4*)(cp + b + 24);
            uint da = ext16(i0, s), db = ext16(i1, s);
            uint dc = ext16(i2, s), dd = ext16(i3, s);
            uint4 ga = tq[da * 6 + p];
            uint4 gb = tq[db * 6 + p];
            uint4 gc = tq[dc * 6 + p];
            uint4 gd = tq[dd * 6 + p];
            ACC8(ga); ACC8(gb); ACC8(gc); ACC8(gd);
        }
        if (b + 16 <= c8) {
            uint4 i0 = *(const uint4*)(cp + b);
            uint4 i1 = *(const uint4*)(cp + b + 8);
            uint da = ext16(i0, s), db = ext16(i1, s);
            uint4 ga = tq[da * 6 + p];
            uint4 gb = tq[db * 6 + p];
            ACC8(ga); ACC8(gb);
            b += 16;
        }
        if (b < c8) {
            uint4 i0 = *(const uint4*)(cp + b);
            uint da = ext16(i0, s);
            uint4 ga = tq[da * 6 + p];
            ACC8(ga);
        }
#undef ACC8
        // fold 8 slots (lane strides 24, 12, 6); lanes 0..5 end with the sum
#define FOLD(OFS)                                                           \
        a0 += __shfl(a0, lane + OFS); a1 += __shfl(a1, lane + OFS);         \
        a2 += __shfl(a2, lane + OFS); a3 += __shfl(a3, lane + OFS);         \
        a4 += __shfl(a4, lane + OFS); a5 += __shfl(a5, lane + OFS);         \
        a6 += __shfl(a6, lane + OFS); a7 += __shfl(a7, lane + OFS);
        FOLD(24); FOLD(12); FOLD(6);
#undef FOLD
        if (s == 0) {   // lanes 0..5, each owns features 8p..8p+7
            float dgi = dis[gw];
            float m = -alpha * dgi;
            float r0 = m * a0, r1 = m * a1, r2 = m * a2, r3 = m * a3;
            float r4 = m * a4, r5 = m * a5, r6 = m * a6, r7 = m * a7;
            if (subH) {
                const float4 s0v = *(const float4*)(subH + gw * D + p * 8);
                const float4 s1v = *(const float4*)(subH + gw * D + p * 8 + 4);
                r0 -= s0v.x; r1 -= s0v.y; r2 -= s0v.z; r3 -= s0v.w;
                r4 -= s1v.x; r5 -= s1v.y; r6 -= s1v.z; r7 -= s1v.w;
            }
            if (dstF) {
                *(float4*)(dstF + gw * D + p * 8) = make_float4(r0, r1, r2, r3);
                *(float4*)(dstF + gw * D + p * 8 + 4) = make_float4(r4, r5, r6, r7);
            }
            if (dstH) {
                float sc = scaleShadow ? dgi : 1.0f;
                __half2 o0 = __floats2half2_rn(sc * r0, sc * r1);
                __half2 o1 = __floats2half2_rn(sc * r2, sc * r3);
                __half2 o2 = __floats2half2_rn(sc * r4, sc * r5);
                __half2 o3 = __floats2half2_rn(sc * r6, sc * r7);
                uint4 o;
                o.x = *(uint*)&o0; o.y = *(uint*)&o1;
                o.z = *(uint*)&o2; o.w = *(uint*)&o3;
                *(uint4*)(dstH + gw * D + p * 8) = o;
            }
        }
    }
}

// ---- out = x@W0 + t1@W1 + t2@W2 + t3h@W3 + bias ----
#define ONB 128
#define TLP 49
__global__ __launch_bounds__(192) void k_out(
        const float* __restrict__ x, const float* __restrict__ t1,
        const float* __restrict__ t2, const __half* __restrict__ t3h,
        const float* __restrict__ W, const float* __restrict__ bias,
        float* __restrict__ out, int n) {
    __shared__ float tlds[ONB * TLP];
    __shared__ float wlds[D * D];
    int tid = threadIdx.x;
    int fg = tid % 6;        // fo group: fo = fg*8 .. +7
    int ng = tid / 6;        // node group: nodes ng*4 .. +3
    int nodeBase = blockIdx.x * ONB;

    float acc[4][8];
    {
        const float4 b0 = *(const float4*)(bias + fg * 8);
        const float4 b1 = *(const float4*)(bias + fg * 8 + 4);
#pragma unroll
        for (int i = 0; i < 4; ++i) {
            acc[i][0] = b0.x; acc[i][1] = b0.y; acc[i][2] = b0.z; acc[i][3] = b0.w;
            acc[i][4] = b1.x; acc[i][5] = b1.y; acc[i][6] = b1.z; acc[i][7] = b1.w;
        }
    }

#pragma unroll
    for (int k = 0; k < KORD; ++k) {
        for (int j = tid; j < D * D / 4; j += 192) {
            float4 v = *(const float4*)(W + k * D * D + j * 4);
            wlds[j * 4 + 0] = v.x; wlds[j * 4 + 1] = v.y;
            wlds[j * 4 + 2] = v.z; wlds[j * 4 + 3] = v.w;
        }
        for (int j = tid; j < ONB * 12; j += 192) {
            int nl = j / 12, c4 = j % 12;
            int node = nodeBase + nl;
            float4 v = make_float4(0.f, 0.f, 0.f, 0.f);
            if (node < n) {
                if (k < 3) {
                    const float* T = (k == 0) ? x : (k == 1) ? t1 : t2;
                    v = *(const float4*)(T + node * D + c4 * 4);
                } else {
                    const __half2* p = (const __half2*)(t3h + node * D + c4 * 4);
                    float2 a = __half22float2(p[0]);
                    float2 b = __half22float2(p[1]);
                    v = make_float4(a.x, a.y, b.x, b.y);
                }
            }
            float* pp = tlds + nl * TLP + c4 * 4;
            pp[0] = v.x; pp[1] = v.y; pp[2] = v.z; pp[3] = v.w;
        }
        __syncthreads();
#pragma unroll 4
        for (int f = 0; f < D; ++f) {
            const float4 w0 = *(const float4*)(wlds + f * D + fg * 8);
            const float4 w1 = *(const float4*)(wlds + f * D + fg * 8 + 4);
            float tv[4];
#pragma unroll
            for (int i = 0; i < 4; ++i) tv[i] = tlds[(ng * 4 + i) * TLP + f];
#pragma unroll
            for (int i = 0; i < 4; ++i) {
                acc[i][0] += tv[i] * w0.x; acc[i][1] += tv[i] * w0.y;
                acc[i][2] += tv[i] * w0.z; acc[i][3] += tv[i] * w0.w;
                acc[i][4] += tv[i] * w1.x; acc[i][5] += tv[i] * w1.y;
                acc[i][6] += tv[i] * w1.z; acc[i][7] += tv[i] * w1.w;
            }
        }
        __syncthreads();
    }

#pragma unroll
    for (int i = 0; i < 4; ++i) {
        int node = nodeBase + ng * 4 + i;
        if (node < n) {
            float4 o0 = make_float4(acc[i][0], acc[i][1], acc[i][2], acc[i][3]);
            float4 o1 = make_float4(acc[i][4], acc[i][5], acc[i][6], acc[i][7]);
            *(float4*)(out + node * D + fg * 8) = o0;
            *(float4*)(out + node * D + fg * 8 + 4) = o1;
        }
    }
}

extern "C" void kernel_launch(void* const* d_in, const int* in_sizes, int n_in,
                              void* d_out, int out_size, void* d_ws, size_t ws_size,
                              hipStream_t stream) {
    const float* x    = (const float*)d_in[0];
    const int*   ei   = (const int*)d_in[1];
    const float* W    = (const float*)d_in[2];
    const float* bias = (const float*)d_in[3];
    float* out = (float*)d_out;

    int n = in_sizes[0] / D;   // 50000
    int E = in_sizes[1] / 2;   // 1.6M
    const int* row  = ei;      // source j
    const int* colp = ei + E;  // target i

    char* ws = (char*)d_ws;
    // region A: bdata (scatter1->scatter2) -> xh (h2->prop1) -> t2h (prop2->prop3)
    // (t2h inherits xh's zeroed sentinel row: same pointer, same layout)
    size_t Abytes = (size_t)E * 4;
    size_t xhBytes = (size_t)(n + 1) * D * 2;   // +sentinel row
    if (xhBytes > Abytes) Abytes = xhBytes;
    Abytes = (Abytes + 255) & ~(size_t)255;
    char* Aptr = ws; ws += Abytes;
    uint*   bdata = (uint*)Aptr;
    __half* xh    = (__half*)Aptr;
    __half* t2h   = (__half*)Aptr;
    uint* coarse  = (uint*)ws; ws += (size_t)NBK * 4;
    int*  basep   = (int*)ws;  ws += (size_t)(NBK + 1) * 4;
    int*  cursor  = (int*)ws;  ws += (size_t)NBK * 4;
    ws = (char*)(((size_t)ws + 255) & ~(size_t)255);
    float* dis    = (float*)ws; ws += (size_t)n * 4;
    int*   offs   = (int*)ws;   ws += (size_t)n * 4;
    int*   cntout = (int*)ws;   ws += (size_t)n * 4;
    int CSRN = E + NBK * PADB + 64;  // padded CSR capacity
    unsigned short* csr = (unsigned short*)ws; ws += ((size_t)CSRN * 2 + 255) & ~(size_t)255;
    // region B: histbuf (hist->reduce) -> t1 fp32 (prop1->...)
    size_t Bbytes = (size_t)HB * 2 * HW * 4;
    size_t t1Bytes = (size_t)n * D * 4;
    if (t1Bytes > Bbytes) Bbytes = t1Bytes;
    char* Bptr = ws; ws += (Bbytes + 255) & ~(size_t)255;
    uint*  histbuf = (uint*)Bptr;
    float* t1      = (float*)Bptr;
    float* t2      = (float*)ws; ws += (size_t)n * D * 4;
    __half* t1h    = (__half*)ws; ws += ((size_t)(n + 1) * D * 2 + 255) & ~(size_t)255;
    __half* t3h    = (__half*)ws; ws += (size_t)n * D * 2;

    hipMemsetAsync(coarse, 0, (size_t)NBK * 4, stream);

    int chunkH = (E + HB - 1) / HB;
    k_hist<<<2 * HB, 1024, 0, stream>>>(row, colp, histbuf, coarse, E, chunkH);
    k_reduce<<<(n / 2 + 255) / 256, 256, 0, stream>>>(histbuf, dis, n / 2);
    k_cscan<<<1, 64, 0, stream>>>(coarse, basep, cursor, NBK);
    int chunk1 = (E + 255) / 256;
    k_scatter1<<<256, 256, 0, stream>>>(row, colp, cursor, bdata, E, chunk1);
    k_scatter2<<<NBK, 256, 0, stream>>>(bdata, basep, offs, cntout, csr, n);
    k_h2<<<((n + 1) * 12 + 255) / 256, 256, 0, stream>>>(x, dis, xh, t1h, n);

    int pblocks = (n + 3) / 4;  // 4 waves (=4 nodes) per 256-thread block
    // t1 = P(x);           shadow t1h scaled by dis
    k_prop<<<pblocks, 256, 0, stream>>>(xh,  nullptr, t1, t1h, offs, cntout, csr, dis, n, 1.0f, 1);
    // t2 = 2 P(t1) - x;    shadow t2h scaled by dis
    k_prop<<<pblocks, 256, 0, stream>>>(t1h, x,       t2, t2h, offs, cntout, csr, dis, n, 2.0f, 1);
    // t3 = 2 P(t2) - t1;   fp16 only, UNSCALED (consumed by k_out)
    k_prop<<<pblocks, 256, 0, stream>>>(t2h, t1, nullptr, t3h, offs, cntout, csr, dis, n, 2.0f, 0);

    k_out<<<(n + ONB - 1) / ONB, 192, 0, stream>>>(x, t1, t2, t3h, W, bias, out, n);
}

// Round 10
// 230.017 us; speedup vs baseline: 1.1502x; 1.1502x over previous
//
#include <hip/hip_runtime.h>
#include <hip/hip_fp16.h>

#define D 48
#define KORD 4
#define RSH 7             // 128 dst ids per bucket
#define RNG 128
#define NBK 391           // ceil(50000/128)
#define HB 64             // histogram chunks
#define HHALF 25000       // node ids per half
#define HW 12500          // packed words per half
#define S1CH 6272         // pass-1 chunk capacity (>= ceil(E/256))
#define MAXB 6144         // max PADDED entries per bucket
#define PADB 960          // per-bucket slack for 8-rounding (multiple of 8)

// ---- outdeg histogram (privatized, no global atomics) + coarse bucket hist ----
__global__ __launch_bounds__(1024) void k_hist(const int* __restrict__ row,
        const int* __restrict__ col, uint* __restrict__ histbuf,
        uint* __restrict__ coarse, int E, int chunk) {
    __shared__ uint hist[HW];     // 50 KB: packed ushort counters for one id-half
    __shared__ uint ch[NBK];
    int k = blockIdx.x >> 1, h = blockIdx.x & 1;
    int tid = threadIdx.x;
    for (int i = tid; i < HW; i += 1024) hist[i] = 0;
    if (h == 0) for (int i = tid; i < NBK; i += 1024) ch[i] = 0;
    __syncthreads();
    int lo = h * HHALF;
    int s = k * chunk, e = min(E, s + chunk);
    for (int i = s + tid; i < e; i += 1024) {
        int r = row[i], c = col[i];
        if (r != c) {
            unsigned rl = (unsigned)(r - lo);
            if (rl < HHALF) atomicAdd(&hist[rl >> 1], 1u << ((rl & 1) * 16));
            if (h == 0) atomicAdd(&ch[c >> RSH], 1u);
        }
    }
    __syncthreads();
    uint* dst = histbuf + (size_t)k * (2 * HW) + (size_t)h * HW;
    for (int i = tid; i < HW; i += 1024) dst[i] = hist[i];
    if (h == 0) for (int i = tid; i < NBK; i += 1024) atomicAdd(&coarse[i], ch[i]);
}

// ---- reduce private histograms -> dis = deg^{-1/2} ----
__global__ void k_reduce(const uint* __restrict__ histbuf, float* __restrict__ dis,
                         int nwords) {
    int t = blockIdx.x * blockDim.x + threadIdx.x;  // word t = nodes 2t,2t+1
    if (t >= nwords) return;
    uint lo = 0, hi = 0;
#pragma unroll 8
    for (int k = 0; k < HB; ++k) {
        uint w = histbuf[(size_t)k * (2 * HW) + t];
        lo += w & 0xFFFFu;
        hi += w >> 16;
    }
    float2 d;
    d.x = lo ? rsqrtf((float)lo) : 0.0f;
    d.y = hi ? rsqrtf((float)hi) : 0.0f;
    *(float2*)(dis + 2 * t) = d;
}

// ---- scan coarse bucket counts -> base, init cursors ----
__global__ void k_cscan(const uint* __restrict__ coarse, int* __restrict__ base,
                        int* __restrict__ cursor, int nbk) {
    int lane = threadIdx.x;
    int carry = 0;
    for (int s = 0; s < nbk; s += 64) {
        int i = s + lane;
        int v = (i < nbk) ? (int)coarse[i] : 0;
        int incl = v;
#pragma unroll
        for (int off = 1; off < 64; off <<= 1) {
            int t = __shfl_up(incl, off);
            if (lane >= off) incl += t;
        }
        if (i < nbk) { int ex = carry + incl - v; base[i] = ex; cursor[i] = ex; }
        carry += __shfl(incl, 63);
    }
    if (lane == 0) base[nbk] = carry;
}

// ---- pass 1: scatter edges into coarse buckets, coalesced run writes (R8 staged) ----
__global__ __launch_bounds__(256) void k_scatter1(const int* __restrict__ row,
        const int* __restrict__ col, int* __restrict__ cursor,
        uint* __restrict__ bdata, int E, int chunk) {
    __shared__ uint cnt[NBK];
    __shared__ uint loc[NBK + 1];
    __shared__ uint cur[NBK];
    __shared__ uint res[NBK];
    __shared__ uint stage[S1CH];
    int tid = threadIdx.x;
    int s = blockIdx.x * chunk, e = min(E, s + chunk);
    for (int i = tid; i < NBK; i += 256) cnt[i] = 0;
    __syncthreads();
    for (int i = s + tid; i < e; i += 256) {
        int r = row[i], c = col[i];
        if (r != c) atomicAdd(&cnt[c >> RSH], 1u);
    }
    __syncthreads();
    if (tid < 64) {  // wave-0 scan of 391 counts
        uint carry = 0;
        for (int b = 0; b < NBK; b += 64) {
            int i = b + tid;
            uint v = (i < NBK) ? cnt[i] : 0;
            uint incl = v;
#pragma unroll
            for (int off = 1; off < 64; off <<= 1) {
                uint t = __shfl_up(incl, off);
                if (tid >= off) incl += t;
            }
            if (i < NBK) loc[i] = carry + incl - v;
            carry += __shfl(incl, 63);
        }
        if (tid == 0) loc[NBK] = carry;
    }
    __syncthreads();
    for (int i = tid; i < NBK; i += 256) {
        uint c = cnt[i];
        res[i] = c ? (uint)atomicAdd(&cursor[i], (int)c) : 0u;
        cur[i] = loc[i];
    }
    __syncthreads();
    for (int i = s + tid; i < e; i += 256) {
        int r = row[i], c = col[i];
        if (r != c) {
            uint slot = atomicAdd(&cur[c >> RSH], 1u);
            stage[slot] = ((uint)c << 16) | (uint)r;
        }
    }
    __syncthreads();
    uint total = loc[NBK];
    for (uint j = tid; j < total; j += 256) {
        int lo2 = 0, hi2 = NBK;  // largest b with loc[b] <= j
        while (hi2 - lo2 > 1) {
            int mid = (lo2 + hi2) >> 1;
            if (loc[mid] <= j) lo2 = mid; else hi2 = mid;
        }
        bdata[res[lo2] + (j - loc[lo2])] = stage[j];
    }
}

// ---- pass 2: per-bucket counting sort -> padded csr (u16, sentinel-filled) ----
__global__ __launch_bounds__(256) void k_scatter2(const uint* __restrict__ bdata,
        const int* __restrict__ base, int* __restrict__ offs, int* __restrict__ cntout,
        unsigned short* __restrict__ csr, int N) {
    __shared__ uint cnt[RNG], locp[RNG], cur[RNG];
    __shared__ uint s_tot;
    __shared__ unsigned short srcbuf[MAXB];
    int b = blockIdx.x, tid = threadIdx.x;
    int s0 = base[b], e2 = base[b + 1];
    int m = e2 - s0;
    int sp = ((s0 + 7) & ~7) + PADB * b;   // padded, 8-aligned region start
    int dstbase = b << RSH;
    for (int i = tid; i < RNG; i += 256) cnt[i] = 0;
    __syncthreads();
    for (int i = tid; i < m; i += 256) {
        uint u = bdata[s0 + i];
        atomicAdd(&cnt[(u >> 16) & (RNG - 1)], 1u);
    }
    __syncthreads();
    if (tid < 64) {  // scan of round8(counts) in wave 0
        uint carry = 0;
        for (int r0 = 0; r0 < RNG; r0 += 64) {
            uint v = (cnt[r0 + tid] + 7u) & ~7u;
            uint incl = v;
#pragma unroll
            for (int off = 1; off < 64; off <<= 1) {
                uint t = __shfl_up(incl, off);
                if (tid >= off) incl += t;
            }
            locp[r0 + tid] = carry + incl - v;
            carry += __shfl(incl, 63);
        }
        if (tid == 0) s_tot = carry;
    }
    __syncthreads();
    uint tot = s_tot;
    if (tid < RNG) {
        int node = dstbase + tid;
        if (node < N) {
            offs[node] = sp + (int)locp[tid];
            cntout[node] = (int)((cnt[tid] + 7u) & ~7u);
        }
        cur[tid] = locp[tid];
    }
    for (uint i = tid; i < tot; i += 256) srcbuf[i] = (unsigned short)N;  // sentinel
    __syncthreads();
    for (int i = tid; i < m; i += 256) {
        uint u = bdata[s0 + i];
        uint slot = atomicAdd(&cur[(u >> 16) & (RNG - 1)], 1u);
        srcbuf[slot] = (unsigned short)(u & 0xFFFFu);
    }
    __syncthreads();
    for (uint i = tid; i < tot; i += 256) csr[sp + i] = srcbuf[i];
}

// ---- x -> fp16 SPLIT shadow tables (24 feats each), pre-scaled by dis[i] ----
// also zeros sentinel rows of xh* and t1h*
__global__ void k_h2(const float* __restrict__ x, const float* __restrict__ dis,
                     __half* __restrict__ xhL, __half* __restrict__ xhH,
                     __half* __restrict__ t1hL, __half* __restrict__ t1hH, int n) {
    int t = blockIdx.x * blockDim.x + threadIdx.x;
    if (t >= (n + 1) * 12) return;
    int node = t / 12, c4 = t % 12;
    __half* xt  = (c4 < 6) ? xhL : xhH;
    __half* t1t = (c4 < 6) ? t1hL : t1hH;
    int co = (c4 < 6) ? c4 * 4 : (c4 - 6) * 4;      // half offset within 24-row
    if (node == n) {  // sentinel rows
        uint2 z = make_uint2(0u, 0u);
        *(uint2*)(xt + node * 24 + co) = z;
        *(uint2*)(t1t + node * 24 + co) = z;
        return;
    }
    float d = dis[node];
    float4 v = *(const float4*)(x + node * D + c4 * 4);
    __half2 h0 = __floats2half2_rn(d * v.x, d * v.y);
    __half2 h1 = __floats2half2_rn(d * v.z, d * v.w);
    uint2 o;
    o.x = *(uint*)&h0; o.y = *(uint*)&h1;
    *(uint2*)(xt + node * 24 + co) = o;
}

// extract 16-bit id j (0..7) from a uint4 of 8 packed u16
__device__ inline uint ext16(const uint4& p, int j) {
    uint w = (j < 4) ? ((j < 2) ? p.x : p.y) : ((j < 6) ? p.z : p.w);
    return (j & 1) ? (w >> 16) : (w & 0xFFFFu);
}

// ---- propagation v6: feature-split tables (24 feats, 48B rows, L2-resident) ----
// 2 waves per node (one per half); lanes 0..47: slot s=lane/12, q=lane%12 (2 halfs)
// r = -alpha * dis[i] * sum_e tab[src_e] - subH ; sentinel rows are zero
__global__ __launch_bounds__(256) void k_prop(const __half* __restrict__ tabL,
        const __half* __restrict__ tabH, const float* __restrict__ subH,
        float* __restrict__ dstF, __half* __restrict__ dhL, __half* __restrict__ dhH,
        const int* __restrict__ offs, const int* __restrict__ cnt,
        const unsigned short* __restrict__ csr, const float* __restrict__ dis,
        int n, float alpha, int scaleShadow) {
    int gwv = (blockIdx.x * blockDim.x + threadIdx.x) >> 6;
    if (gwv >= 2 * n) return;
    gwv = __builtin_amdgcn_readfirstlane(gwv);
    const int node = gwv >> 1, hf = gwv & 1;
    const __half* tab = hf ? tabH : tabL;
    const int lane = threadIdx.x & 63;
    const int s = lane / 12;          // edge slot 0..3 (lanes 48..63 idle)
    const int q = lane % 12;          // halfs 2q,2q+1 of the 24-row
    const int off = __builtin_amdgcn_readfirstlane(offs[node]);
    const int c8 = __builtin_amdgcn_readfirstlane(cnt[node]);  // multiple of 8
    float a0 = 0.f, a1 = 0.f;
    if (lane < 48) {
        const unsigned short* cp = csr + off;   // 16B-aligned
#define GATHER8(PK)                                                         \
        {                                                                   \
            uint ia = ext16(PK, s), ib = ext16(PK, s + 4);                  \
            uint ga = *(const uint*)(tab + ia * 24 + q * 2);                \
            uint gb = *(const uint*)(tab + ib * 24 + q * 2);                \
            float2 fa = __half22float2(*(__half2*)&ga);                     \
            float2 fb = __half22float2(*(__half2*)&gb);                     \
            a0 += fa.x + fb.x; a1 += fa.y + fb.y;                           \
        }
        int b = 0;
        for (; b + 32 <= c8; b += 32) {   // 8 gathers in flight
            uint4 p0 = *(const uint4*)(cp + b);
            uint4 p1 = *(const uint4*)(cp + b + 8);
            uint4 p2 = *(const uint4*)(cp + b + 16);
            uint4 p3 = *(const uint4*)(cp + b + 24);
            GATHER8(p0); GATHER8(p1); GATHER8(p2); GATHER8(p3);
        }
        if (b + 16 <= c8) {
            uint4 p0 = *(const uint4*)(cp + b);
            uint4 p1 = *(const uint4*)(cp + b + 8);
            GATHER8(p0); GATHER8(p1);
            b += 16;
        }
        if (b < c8) {
            uint4 p0 = *(const uint4*)(cp + b);
            GATHER8(p0);
        }
#undef GATHER8
        // reduce 4 slots (lane strides 24, 12); lanes 0..11 end with the sum
        a0 += __shfl(a0, lane + 24); a1 += __shfl(a1, lane + 24);
        a0 += __shfl(a0, lane + 12); a1 += __shfl(a1, lane + 12);
        if (s == 0) {   // lanes 0..11, each owns features hf*24 + 2q, 2q+1
            float dgi = dis[node];
            float m = -alpha * dgi;
            float r0 = m * a0, r1 = m * a1;
            if (subH) {
                float2 sv = *(const float2*)(subH + node * D + hf * 24 + q * 2);
                r0 -= sv.x; r1 -= sv.y;
            }
            if (dstF) *(float2*)(dstF + node * D + hf * 24 + q * 2) = make_float2(r0, r1);
            __half* dh = hf ? dhH : dhL;
            if (dh) {
                float sc = scaleShadow ? dgi : 1.0f;
                __half2 o = __floats2half2_rn(sc * r0, sc * r1);
                *(uint*)(dh + node * 24 + q * 2) = *(uint*)&o;
            }
        }
    }
}

// ---- out = x@W0 + t1@W1 + t2@W2 + t3h@W3 + bias ----
#define ONB 128
#define TLP 49
__global__ __launch_bounds__(192) void k_out(
        const float* __restrict__ x, const float* __restrict__ t1,
        const float* __restrict__ t2, const __half* __restrict__ t3hL,
        const __half* __restrict__ t3hH,
        const float* __restrict__ W, const float* __restrict__ bias,
        float* __restrict__ out, int n) {
    __shared__ float tlds[ONB * TLP];
    __shared__ float wlds[D * D];
    int tid = threadIdx.x;
    int fg = tid % 6;        // fo group: fo = fg*8 .. +7
    int ng = tid / 6;        // node group: nodes ng*4 .. +3
    int nodeBase = blockIdx.x * ONB;

    float acc[4][8];
    {
        const float4 b0 = *(const float4*)(bias + fg * 8);
        const float4 b1 = *(const float4*)(bias + fg * 8 + 4);
#pragma unroll
        for (int i = 0; i < 4; ++i) {
            acc[i][0] = b0.x; acc[i][1] = b0.y; acc[i][2] = b0.z; acc[i][3] = b0.w;
            acc[i][4] = b1.x; acc[i][5] = b1.y; acc[i][6] = b1.z; acc[i][7] = b1.w;
        }
    }

#pragma unroll
    for (int k = 0; k < KORD; ++k) {
        for (int j = tid; j < D * D / 4; j += 192) {
            float4 v = *(const float4*)(W + k * D * D + j * 4);
            wlds[j * 4 + 0] = v.x; wlds[j * 4 + 1] = v.y;
            wlds[j * 4 + 2] = v.z; wlds[j * 4 + 3] = v.w;
        }
        for (int j = tid; j < ONB * 12; j += 192) {
            int nl = j / 12, c4 = j % 12;
            int node = nodeBase + nl;
            float4 v = make_float4(0.f, 0.f, 0.f, 0.f);
            if (node < n) {
                if (k < 3) {
                    const float* T = (k == 0) ? x : (k == 1) ? t1 : t2;
                    v = *(const float4*)(T + node * D + c4 * 4);
                } else {
                    const __half* t3t = (c4 < 6) ? t3hL : t3hH;
                    int co = (c4 < 6) ? c4 * 4 : (c4 - 6) * 4;
                    uint2 u = *(const uint2*)(t3t + node * 24 + co);
                    float2 a = __half22float2(*(__half2*)&u.x);
                    float2 b = __half22float2(*(__half2*)&u.y);
                    v = make_float4(a.x, a.y, b.x, b.y);
                }
            }
            float* pp = tlds + nl * TLP + c4 * 4;
            pp[0] = v.x; pp[1] = v.y; pp[2] = v.z; pp[3] = v.w;
        }
        __syncthreads();
#pragma unroll 4
        for (int f = 0; f < D; ++f) {
            const float4 w0 = *(const float4*)(wlds + f * D + fg * 8);
            const float4 w1 = *(const float4*)(wlds + f * D + fg * 8 + 4);
            float tv[4];
#pragma unroll
            for (int i = 0; i < 4; ++i) tv[i] = tlds[(ng * 4 + i) * TLP + f];
#pragma unroll
            for (int i = 0; i < 4; ++i) {
                acc[i][0] += tv[i] * w0.x; acc[i][1] += tv[i] * w0.y;
                acc[i][2] += tv[i] * w0.z; acc[i][3] += tv[i] * w0.w;
                acc[i][4] += tv[i] * w1.x; acc[i][5] += tv[i] * w1.y;
                acc[i][6] += tv[i] * w1.z; acc[i][7] += tv[i] * w1.w;
            }
        }
        __syncthreads();
    }

#pragma unroll
    for (int i = 0; i < 4; ++i) {
        int node = nodeBase + ng * 4 + i;
        if (node < n) {
            float4 o0 = make_float4(acc[i][0], acc[i][1], acc[i][2], acc[i][3]);
            float4 o1 = make_float4(acc[i][4], acc[i][5], acc[i][6], acc[i][7]);
            *(float4*)(out + node * D + fg * 8) = o0;
            *(float4*)(out + node * D + fg * 8 + 4) = o1;
        }
    }
}

extern "C" void kernel_launch(void* const* d_in, const int* in_sizes, int n_in,
                              void* d_out, int out_size, void* d_ws, size_t ws_size,
                              hipStream_t stream) {
    const float* x    = (const float*)d_in[0];
    const int*   ei   = (const int*)d_in[1];
    const float* W    = (const float*)d_in[2];
    const float* bias = (const float*)d_in[3];
    float* out = (float*)d_out;

    int n = in_sizes[0] / D;   // 50000
    int E = in_sizes[1] / 2;   // 1.6M
    const int* row  = ei;      // source j
    const int* colp = ei + E;  // target i

    char* ws = (char*)d_ws;
    // region A: bdata (scatter1->scatter2) -> xh split (h2->prop1) -> t2h split
    size_t Abytes = (size_t)E * 4;
    size_t xhBytes = (size_t)(n + 1) * D * 2;   // both halves + sentinel rows
    if (xhBytes > Abytes) Abytes = xhBytes;
    Abytes = (Abytes + 255) & ~(size_t)255;
    char* Aptr = ws; ws += Abytes;
    uint*   bdata = (uint*)Aptr;
    __half* xhL   = (__half*)Aptr;
    __half* xhH   = xhL + (size_t)(n + 1) * 24;
    __half* t2hL  = (__half*)Aptr;            // same addrs; lifetimes disjoint
    __half* t2hH  = t2hL + (size_t)(n + 1) * 24;
    uint* coarse  = (uint*)ws; ws += (size_t)NBK * 4;
    int*  basep   = (int*)ws;  ws += (size_t)(NBK + 1) * 4;
    int*  cursor  = (int*)ws;  ws += (size_t)NBK * 4;
    ws = (char*)(((size_t)ws + 255) & ~(size_t)255);
    float* dis    = (float*)ws; ws += (size_t)n * 4;
    int*   offs   = (int*)ws;   ws += (size_t)n * 4;
    int*   cntout = (int*)ws;   ws += (size_t)n * 4;
    int CSRN = E + NBK * PADB + 64;  // padded CSR capacity
    unsigned short* csr = (unsigned short*)ws; ws += ((size_t)CSRN * 2 + 255) & ~(size_t)255;
    // region B: histbuf (hist->reduce) -> t1 fp32 (prop1->...)
    size_t Bbytes = (size_t)HB * 2 * HW * 4;
    size_t t1Bytes = (size_t)n * D * 4;
    if (t1Bytes > Bbytes) Bbytes = t1Bytes;
    char* Bptr = ws; ws += (Bbytes + 255) & ~(size_t)255;
    uint*  histbuf = (uint*)Bptr;
    float* t1      = (float*)Bptr;
    float* t2      = (float*)ws; ws += (size_t)n * D * 4;
    __half* t1hL   = (__half*)ws; ws += ((size_t)(n + 1) * D * 2 + 255) & ~(size_t)255;
    __half* t1hH   = t1hL + (size_t)(n + 1) * 24;
    __half* t3hL   = (__half*)ws; ws += (size_t)n * D * 2;
    __half* t3hH   = t3hL + (size_t)n * 24;

    hipMemsetAsync(coarse, 0, (size_t)NBK * 4, stream);

    int chunkH = (E + HB - 1) / HB;
    k_hist<<<2 * HB, 1024, 0, stream>>>(row, colp, histbuf, coarse, E, chunkH);
    k_reduce<<<(n / 2 + 255) / 256, 256, 0, stream>>>(histbuf, dis, n / 2);
    k_cscan<<<1, 64, 0, stream>>>(coarse, basep, cursor, NBK);
    int chunk1 = (E + 255) / 256;
    k_scatter1<<<256, 256, 0, stream>>>(row, colp, cursor, bdata, E, chunk1);
    k_scatter2<<<NBK, 256, 0, stream>>>(bdata, basep, offs, cntout, csr, n);
    k_h2<<<((n + 1) * 12 + 255) / 256, 256, 0, stream>>>(x, dis, xhL, xhH, t1hL, t1hH, n);

    int pblocks = (2 * n + 3) / 4;  // 2 waves per node, 4 waves per block
    // t1 = P(x);           shadows t1hL/H scaled by dis
    k_prop<<<pblocks, 256, 0, stream>>>(xhL, xhH, nullptr, t1, t1hL, t1hH,
                                        offs, cntout, csr, dis, n, 1.0f, 1);
    // t2 = 2 P(t1) - x;    shadows t2hL/H scaled by dis
    k_prop<<<pblocks, 256, 0, stream>>>(t1hL, t1hH, x, t2, t2hL, t2hH,
                                        offs, cntout, csr, dis, n, 2.0f, 1);
    // t3 = 2 P(t2) - t1;   fp16 only, UNSCALED (consumed by k_out)
    k_prop<<<pblocks, 256, 0, stream>>>(t2hL, t2hH, t1, nullptr, t3hL, t3hH,
                                        offs, cntout, csr, dis, n, 2.0f, 0);

    k_out<<<(n + ONB - 1) / ONB, 192, 0, stream>>>(x, t1, t2, t3hL, t3hH, W, bias, out, n);
}

// Round 11
// 172.856 us; speedup vs baseline: 1.5306x; 1.3307x over previous
//
#include <hip/hip_runtime.h>
#include <hip/hip_fp16.h>

#define D 48
#define KORD 4
#define RSH 7             // 128 dst ids per bucket
#define RNG 128
#define NBK 391           // ceil(50000/128)
#define HB 64             // histogram chunks
#define HHALF 25000       // node ids per half
#define HW 12500          // packed words per half
#define S1CH 6272         // pass-1 chunk capacity (>= ceil(E/256))
#define MAXB 6144         // max PADDED entries per bucket
#define PADB 960          // per-bucket slack for 8-rounding (multiple of 8)

// ---- outdeg histogram (privatized, no global atomics) + coarse bucket hist ----
__global__ __launch_bounds__(1024) void k_hist(const int* __restrict__ row,
        const int* __restrict__ col, uint* __restrict__ histbuf,
        uint* __restrict__ coarse, int E, int chunk) {
    __shared__ uint hist[HW];     // 50 KB: packed ushort counters for one id-half
    __shared__ uint ch[NBK];
    int k = blockIdx.x >> 1, h = blockIdx.x & 1;
    int tid = threadIdx.x;
    for (int i = tid; i < HW; i += 1024) hist[i] = 0;
    if (h == 0) for (int i = tid; i < NBK; i += 1024) ch[i] = 0;
    __syncthreads();
    int lo = h * HHALF;
    int s = k * chunk, e = min(E, s + chunk);
    for (int i = s + tid; i < e; i += 1024) {
        int r = row[i], c = col[i];
        if (r != c) {
            unsigned rl = (unsigned)(r - lo);
            if (rl < HHALF) atomicAdd(&hist[rl >> 1], 1u << ((rl & 1) * 16));
            if (h == 0) atomicAdd(&ch[c >> RSH], 1u);
        }
    }
    __syncthreads();
    uint* dst = histbuf + (size_t)k * (2 * HW) + (size_t)h * HW;
    for (int i = tid; i < HW; i += 1024) dst[i] = hist[i];
    if (h == 0) for (int i = tid; i < NBK; i += 1024) atomicAdd(&coarse[i], ch[i]);
}

// ---- reduce private histograms -> dis = deg^{-1/2}; block 0 also scans coarse ----
__global__ void k_reduce(const uint* __restrict__ histbuf, float* __restrict__ dis,
                         int nwords, const uint* __restrict__ coarse,
                         int* __restrict__ base, int* __restrict__ cursor, int nbk) {
    int t = blockIdx.x * blockDim.x + threadIdx.x;  // word t = nodes 2t,2t+1
    if (t < nwords) {
        uint lo = 0, hi = 0;
#pragma unroll 8
        for (int k = 0; k < HB; ++k) {
            uint w = histbuf[(size_t)k * (2 * HW) + t];
            lo += w & 0xFFFFu;
            hi += w >> 16;
        }
        float2 d;
        d.x = lo ? rsqrtf((float)lo) : 0.0f;
        d.y = hi ? rsqrtf((float)hi) : 0.0f;
        *(float2*)(dis + 2 * t) = d;
    }
    // fold-in of the coarse-bucket exclusive scan (independent data)
    if (blockIdx.x == 0 && threadIdx.x < 64) {
        int lane = threadIdx.x;
        int carry = 0;
        for (int s = 0; s < nbk; s += 64) {
            int i = s + lane;
            int v = (i < nbk) ? (int)coarse[i] : 0;
            int incl = v;
#pragma unroll
            for (int off = 1; off < 64; off <<= 1) {
                int tt = __shfl_up(incl, off);
                if (lane >= off) incl += tt;
            }
            if (i < nbk) { int ex = carry + incl - v; base[i] = ex; cursor[i] = ex; }
            carry += __shfl(incl, 63);
        }
        if (lane == 0) base[nbk] = carry;
    }
}

// ---- pass 1: scatter edges into coarse buckets, coalesced run writes ----
// output phase: bucket id decoded from the staged value (no binary search)
__global__ __launch_bounds__(256) void k_scatter1(const int* __restrict__ row,
        const int* __restrict__ col, int* __restrict__ cursor,
        uint* __restrict__ bdata, int E, int chunk) {
    __shared__ uint cnt[NBK];
    __shared__ uint loc[NBK + 1];
    __shared__ uint cur[NBK];
    __shared__ uint res[NBK];
    __shared__ uint stage[S1CH];
    int tid = threadIdx.x;
    int s = blockIdx.x * chunk, e = min(E, s + chunk);
    for (int i = tid; i < NBK; i += 256) cnt[i] = 0;
    __syncthreads();
    for (int i = s + tid; i < e; i += 256) {
        int r = row[i], c = col[i];
        if (r != c) atomicAdd(&cnt[c >> RSH], 1u);
    }
    __syncthreads();
    if (tid < 64) {  // wave-0 scan of 391 counts
        uint carry = 0;
        for (int b = 0; b < NBK; b += 64) {
            int i = b + tid;
            uint v = (i < NBK) ? cnt[i] : 0;
            uint incl = v;
#pragma unroll
            for (int off = 1; off < 64; off <<= 1) {
                uint t = __shfl_up(incl, off);
                if (tid >= off) incl += t;
            }
            if (i < NBK) loc[i] = carry + incl - v;
            carry += __shfl(incl, 63);
        }
        if (tid == 0) loc[NBK] = carry;
    }
    __syncthreads();
    for (int i = tid; i < NBK; i += 256) {
        uint c = cnt[i];
        res[i] = c ? (uint)atomicAdd(&cursor[i], (int)c) : 0u;
        cur[i] = loc[i];
    }
    __syncthreads();
    for (int i = s + tid; i < e; i += 256) {
        int r = row[i], c = col[i];
        if (r != c) {
            uint slot = atomicAdd(&cur[c >> RSH], 1u);
            stage[slot] = ((uint)c << 16) | (uint)r;
        }
    }
    __syncthreads();
    uint total = loc[NBK];
    for (uint j = tid; j < total; j += 256) {
        uint v = stage[j];
        uint b = v >> (16 + RSH);           // bucket id from staged dst
        bdata[res[b] + (j - loc[b])] = v;
    }
}

// ---- pass 2: per-bucket counting sort -> padded csr (u16, sentinel-filled) ----
// per-node region rounded to 8 entries, 8-aligned start; pads = sentinel id N
__global__ __launch_bounds__(256) void k_scatter2(const uint* __restrict__ bdata,
        const int* __restrict__ base, int* __restrict__ offs, int* __restrict__ cntout,
        unsigned short* __restrict__ csr, int N) {
    __shared__ uint cnt[RNG], locp[RNG], cur[RNG];
    __shared__ uint s_tot;
    __shared__ unsigned short srcbuf[MAXB];
    int b = blockIdx.x, tid = threadIdx.x;
    int s0 = base[b], e2 = base[b + 1];
    int m = e2 - s0;
    int sp = ((s0 + 7) & ~7) + PADB * b;   // padded, 8-aligned region start
    int dstbase = b << RSH;
    for (int i = tid; i < RNG; i += 256) cnt[i] = 0;
    __syncthreads();
    for (int i = tid; i < m; i += 256) {
        uint u = bdata[s0 + i];
        atomicAdd(&cnt[(u >> 16) & (RNG - 1)], 1u);
    }
    __syncthreads();
    if (tid < 64) {  // scan of round8(counts) in wave 0
        uint carry = 0;
        for (int r0 = 0; r0 < RNG; r0 += 64) {
            uint v = (cnt[r0 + tid] + 7u) & ~7u;
            uint incl = v;
#pragma unroll
            for (int off = 1; off < 64; off <<= 1) {
                uint t = __shfl_up(incl, off);
                if (tid >= off) incl += t;
            }
            locp[r0 + tid] = carry + incl - v;
            carry += __shfl(incl, 63);
        }
        if (tid == 0) s_tot = carry;
    }
    __syncthreads();
    uint tot = s_tot;
    if (tid < RNG) {
        int node = dstbase + tid;
        if (node < N) {
            offs[node] = sp + (int)locp[tid];
            cntout[node] = (int)((cnt[tid] + 7u) & ~7u);
        }
        cur[tid] = locp[tid];
    }
    for (uint i = tid; i < tot; i += 256) srcbuf[i] = (unsigned short)N;  // sentinel
    __syncthreads();
    for (int i = tid; i < m; i += 256) {
        uint u = bdata[s0 + i];
        uint slot = atomicAdd(&cur[(u >> 16) & (RNG - 1)], 1u);
        srcbuf[slot] = (unsigned short)(u & 0xFFFFu);
    }
    __syncthreads();
    for (uint i = tid; i < tot; i += 256) csr[sp + i] = srcbuf[i];
}

// ---- x -> fp16 shadow, pre-scaled by dis[i]; sentinel rows (xh, t1h) = zeros ----
__global__ void k_h2(const float* __restrict__ x, const float* __restrict__ dis,
                     __half* __restrict__ xh, __half* __restrict__ t1h, int n) {
    int t = blockIdx.x * blockDim.x + threadIdx.x;
    if (t >= (n + 1) * 12) return;
    int node = t / 12, c4 = t % 12;
    if (node == n) {  // sentinel rows
        uint2 z = make_uint2(0u, 0u);
        *(uint2*)(xh + node * D + c4 * 4) = z;
        *(uint2*)(t1h + node * D + c4 * 4) = z;
        return;
    }
    float d = dis[node];
    float4 v = *(const float4*)(x + node * D + c4 * 4);
    __half2* p = (__half2*)(xh + node * D + c4 * 4);
    p[0] = __floats2half2_rn(d * v.x, d * v.y);
    p[1] = __floats2half2_rn(d * v.z, d * v.w);
}

// extract 16-bit id j (0..7) from a uint4 of 8 packed u16
__device__ inline uint ext16(const uint4& p, int j) {
    uint w = (j < 4) ? ((j < 2) ? p.x : p.y) : ((j < 6) ? p.z : p.w);
    return (j & 1) ? (w >> 16) : (w & 0xFFFFu);
}

// ---- propagation v4 (R8 known-good): pad-8 CSR; 32/16/8-edge batches ----
// wave per node; lanes 0..47: slot s=lane/12 (edge), q=lane%12 (feature quad)
// r = -alpha * dis[i] * sum_e tab[src_e] - subH ; sentinel rows are zero
__global__ __launch_bounds__(256) void k_prop(const __half* __restrict__ tab,
        const float* __restrict__ subH, float* __restrict__ dstF,
        __half* __restrict__ dstH, const int* __restrict__ offs,
        const int* __restrict__ cnt, const unsigned short* __restrict__ csr,
        const float* __restrict__ dis, int n, float alpha, int scaleShadow) {
    int gw = (blockIdx.x * blockDim.x + threadIdx.x) >> 6;
    if (gw >= n) return;
    gw = __builtin_amdgcn_readfirstlane(gw);
    const int lane = threadIdx.x & 63;
    const int s = lane / 12;          // edge slot 0..3 (lanes 48..63 idle)
    const int q = lane % 12;          // halfs 4q..4q+3 of the row
    const int off = __builtin_amdgcn_readfirstlane(offs[gw]);
    const int c8 = __builtin_amdgcn_readfirstlane(cnt[gw]);  // multiple of 8
    float4 acc = make_float4(0.f, 0.f, 0.f, 0.f);
    if (lane < 48) {
        const unsigned short* cp = csr + off;   // 16B-aligned
#define GATHER8(PK)                                                         \
        {                                                                   \
            uint ia = ext16(PK, s), ib = ext16(PK, s + 4);                  \
            uint2 ga = *(const uint2*)(tab + ia * D + q * 4);               \
            uint2 gb = *(const uint2*)(tab + ib * D + q * 4);               \
            float2 fa0 = __half22float2(*(__half2*)&ga.x);                  \
            float2 fa1 = __half22float2(*(__half2*)&ga.y);                  \
            float2 fb0 = __half22float2(*(__half2*)&gb.x);                  \
            float2 fb1 = __half22float2(*(__half2*)&gb.y);                  \
            acc.x += fa0.x + fb0.x; acc.y += fa0.y + fb0.y;                 \
            acc.z += fa1.x + fb1.x; acc.w += fa1.y + fb1.y;                 \
        }
        int b = 0;
        for (; b + 32 <= c8; b += 32) {   // 8 gathers in flight
            uint4 p0 = *(const uint4*)(cp + b);
            uint4 p1 = *(const uint4*)(cp + b + 8);
            uint4 p2 = *(const uint4*)(cp + b + 16);
            uint4 p3 = *(const uint4*)(cp + b + 24);
            GATHER8(p0); GATHER8(p1); GATHER8(p2); GATHER8(p3);
        }
        if (b + 16 <= c8) {
            uint4 p0 = *(const uint4*)(cp + b);
            uint4 p1 = *(const uint4*)(cp + b + 8);
            GATHER8(p0); GATHER8(p1);
            b += 16;
        }
        if (b < c8) {
            uint4 p0 = *(const uint4*)(cp + b);
            GATHER8(p0);
        }
#undef GATHER8
        // reduce 4 slots (lane offsets 0,12,24,36)
        acc.x += __shfl(acc.x, lane + 24); acc.y += __shfl(acc.y, lane + 24);
        acc.z += __shfl(acc.z, lane + 24); acc.w += __shfl(acc.w, lane + 24);
        acc.x += __shfl(acc.x, lane + 12); acc.y += __shfl(acc.y, lane + 12);
        acc.z += __shfl(acc.z, lane + 12); acc.w += __shfl(acc.w, lane + 12);
        if (s == 0) {
            float dgi = dis[gw];
            float4 r;
            r.x = -alpha * dgi * acc.x; r.y = -alpha * dgi * acc.y;
            r.z = -alpha * dgi * acc.z; r.w = -alpha * dgi * acc.w;
            if (subH) {
                float4 sv = *(const float4*)(subH + gw * D + q * 4);
                r.x -= sv.x; r.y -= sv.y; r.z -= sv.z; r.w -= sv.w;
            }
            if (dstF) *(float4*)(dstF + gw * D + q * 4) = r;
            if (dstH) {
                float sc = scaleShadow ? dgi : 1.0f;
                __half2 o0 = __floats2half2_rn(sc * r.x, sc * r.y);
                __half2 o1 = __floats2half2_rn(sc * r.z, sc * r.w);
                uint2 o;
                o.x = *(uint*)&o0; o.y = *(uint*)&o1;
                *(uint2*)(dstH + gw * D + q * 4) = o;
            }
        }
    }
}

// ---- out = x@W0 + t1@W1 + t2@W2 + t3h@W3 + bias ----
#define ONB 128
#define TLP 49
__global__ __launch_bounds__(192) void k_out(
        const float* __restrict__ x, const float* __restrict__ t1,
        const float* __restrict__ t2, const __half* __restrict__ t3h,
        const float* __restrict__ W, const float* __restrict__ bias,
        float* __restrict__ out, int n) {
    __shared__ float tlds[ONB * TLP];
    __shared__ float wlds[D * D];
    int tid = threadIdx.x;
    int fg = tid % 6;        // fo group: fo = fg*8 .. +7
    int ng = tid / 6;        // node group: nodes ng*4 .. +3
    int nodeBase = blockIdx.x * ONB;

    float acc[4][8];
    {
        const float4 b0 = *(const float4*)(bias + fg * 8);
        const float4 b1 = *(const float4*)(bias + fg * 8 + 4);
#pragma unroll
        for (int i = 0; i < 4; ++i) {
            acc[i][0] = b0.x; acc[i][1] = b0.y; acc[i][2] = b0.z; acc[i][3] = b0.w;
            acc[i][4] = b1.x; acc[i][5] = b1.y; acc[i][6] = b1.z; acc[i][7] = b1.w;
        }
    }

#pragma unroll
    for (int k = 0; k < KORD; ++k) {
        for (int j = tid; j < D * D / 4; j += 192) {
            float4 v = *(const float4*)(W + k * D * D + j * 4);
            wlds[j * 4 + 0] = v.x; wlds[j * 4 + 1] = v.y;
            wlds[j * 4 + 2] = v.z; wlds[j * 4 + 3] = v.w;
        }
        for (int j = tid; j < ONB * 12; j += 192) {
            int nl = j / 12, c4 = j % 12;
            int node = nodeBase + nl;
            float4 v = make_float4(0.f, 0.f, 0.f, 0.f);
            if (node < n) {
                if (k < 3) {
                    const float* T = (k == 0) ? x : (k == 1) ? t1 : t2;
                    v = *(const float4*)(T + node * D + c4 * 4);
                } else {
                    const __half2* p = (const __half2*)(t3h + node * D + c4 * 4);
                    float2 a = __half22float2(p[0]);
                    float2 b = __half22float2(p[1]);
                    v = make_float4(a.x, a.y, b.x, b.y);
                }
            }
            float* pp = tlds + nl * TLP + c4 * 4;
            pp[0] = v.x; pp[1] = v.y; pp[2] = v.z; pp[3] = v.w;
        }
        __syncthreads();
#pragma unroll 4
        for (int f = 0; f < D; ++f) {
            const float4 w0 = *(const float4*)(wlds + f * D + fg * 8);
            const float4 w1 = *(const float4*)(wlds + f * D + fg * 8 + 4);
            float tv[4];
#pragma unroll
            for (int i = 0; i < 4; ++i) tv[i] = tlds[(ng * 4 + i) * TLP + f];
#pragma unroll
            for (int i = 0; i < 4; ++i) {
                acc[i][0] += tv[i] * w0.x; acc[i][1] += tv[i] * w0.y;
                acc[i][2] += tv[i] * w0.z; acc[i][3] += tv[i] * w0.w;
                acc[i][4] += tv[i] * w1.x; acc[i][5] += tv[i] * w1.y;
                acc[i][6] += tv[i] * w1.z; acc[i][7] += tv[i] * w1.w;
            }
        }
        __syncthreads();
    }

#pragma unroll
    for (int i = 0; i < 4; ++i) {
        int node = nodeBase + ng * 4 + i;
        if (node < n) {
            float4 o0 = make_float4(acc[i][0], acc[i][1], acc[i][2], acc[i][3]);
            float4 o1 = make_float4(acc[i][4], acc[i][5], acc[i][6], acc[i][7]);
            *(float4*)(out + node * D + fg * 8) = o0;
            *(float4*)(out + node * D + fg * 8 + 4) = o1;
        }
    }
}

extern "C" void kernel_launch(void* const* d_in, const int* in_sizes, int n_in,
                              void* d_out, int out_size, void* d_ws, size_t ws_size,
                              hipStream_t stream) {
    const float* x    = (const float*)d_in[0];
    const int*   ei   = (const int*)d_in[1];
    const float* W    = (const float*)d_in[2];
    const float* bias = (const float*)d_in[3];
    float* out = (float*)d_out;

    int n = in_sizes[0] / D;   // 50000
    int E = in_sizes[1] / 2;   // 1.6M
    const int* row  = ei;      // source j
    const int* colp = ei + E;  // target i

    char* ws = (char*)d_ws;
    // region A: bdata (scatter1->scatter2) -> xh (h2->prop1) -> t2h (prop2->prop3)
    // (t2h inherits xh's zeroed sentinel row: same pointer, same layout)
    size_t Abytes = (size_t)E * 4;
    size_t xhBytes = (size_t)(n + 1) * D * 2;   // +sentinel row
    if (xhBytes > Abytes) Abytes = xhBytes;
    Abytes = (Abytes + 255) & ~(size_t)255;
    char* Aptr = ws; ws += Abytes;
    uint*   bdata = (uint*)Aptr;
    __half* xh    = (__half*)Aptr;
    __half* t2h   = (__half*)Aptr;
    uint* coarse  = (uint*)ws; ws += (size_t)NBK * 4;
    int*  basep   = (int*)ws;  ws += (size_t)(NBK + 1) * 4;
    int*  cursor  = (int*)ws;  ws += (size_t)NBK * 4;
    ws = (char*)(((size_t)ws + 255) & ~(size_t)255);
    float* dis    = (float*)ws; ws += (size_t)n * 4;
    int*   offs   = (int*)ws;   ws += (size_t)n * 4;
    int*   cntout = (int*)ws;   ws += (size_t)n * 4;
    int CSRN = E + NBK * PADB + 64;  // padded CSR capacity
    unsigned short* csr = (unsigned short*)ws; ws += ((size_t)CSRN * 2 + 255) & ~(size_t)255;
    // region B: histbuf (hist->reduce) -> t1 fp32 (prop1->...)
    size_t Bbytes = (size_t)HB * 2 * HW * 4;
    size_t t1Bytes = (size_t)n * D * 4;
    if (t1Bytes > Bbytes) Bbytes = t1Bytes;
    char* Bptr = ws; ws += (Bbytes + 255) & ~(size_t)255;
    uint*  histbuf = (uint*)Bptr;
    float* t1      = (float*)Bptr;
    float* t2      = (float*)ws; ws += (size_t)n * D * 4;
    __half* t1h    = (__half*)ws; ws += ((size_t)(n + 1) * D * 2 + 255) & ~(size_t)255;
    __half* t3h    = (__half*)ws; ws += (size_t)n * D * 2;

    hipMemsetAsync(coarse, 0, (size_t)NBK * 4, stream);

    int chunkH = (E + HB - 1) / HB;
    k_hist<<<2 * HB, 1024, 0, stream>>>(row, colp, histbuf, coarse, E, chunkH);
    k_reduce<<<(n / 2 + 255) / 256, 256, 0, stream>>>(histbuf, dis, n / 2,
                                                      coarse, basep, cursor, NBK);
    int chunk1 = (E + 255) / 256;
    k_scatter1<<<256, 256, 0, stream>>>(row, colp, cursor, bdata, E, chunk1);
    k_scatter2<<<NBK, 256, 0, stream>>>(bdata, basep, offs, cntout, csr, n);
    k_h2<<<((n + 1) * 12 + 255) / 256, 256, 0, stream>>>(x, dis, xh, t1h, n);

    int pblocks = (n + 3) / 4;  // 4 waves (=4 nodes) per 256-thread block
    // t1 = P(x);           shadow t1h scaled by dis
    k_prop<<<pblocks, 256, 0, stream>>>(xh,  nullptr, t1, t1h, offs, cntout, csr, dis, n, 1.0f, 1);
    // t2 = 2 P(t1) - x;    shadow t2h scaled by dis
    k_prop<<<pblocks, 256, 0, stream>>>(t1h, x,       t2, t2h, offs, cntout, csr, dis, n, 2.0f, 1);
    // t3 = 2 P(t2) - t1;   fp16 only, UNSCALED (consumed by k_out)
    k_prop<<<pblocks, 256, 0, stream>>>(t2h, t1, nullptr, t3h, offs, cntout, csr, dis, n, 2.0f, 0);

    k_out<<<(n + ONB - 1) / ONB, 192, 0, stream>>>(x, t1, t2, t3h, W, bias, out, n);
}